// Round 3
// baseline (10.945 us; speedup 1.0000x reference)
//
#include <hip/hip_runtime.h>

// DipolePredictorE3NN: fused TP-scalar-gate + mean-pool + 3->128->3 MLP.
// One block per batch element b, 128 threads.
// R3: stage feats/coors via LDS so global loads are lane-contiguous float4
// (coalesced); compute phase reads rows from LDS (<=2-way bank alias = free).
// adj_mat (d_in[2]) is unused by the reference.

#define BLOCK 128
#define NSC 7
#define HID 128

__global__ __launch_bounds__(BLOCK) void dipole_e3nn_kernel(
    const float* __restrict__ feats,   // [B, N, 7]
    const float* __restrict__ coors,   // [B, N, 3]
    const float* __restrict__ W_tp,    // [7]
    const float* __restrict__ W1,      // [128, 3] row-major
    const float* __restrict__ b1,      // [128]
    const float* __restrict__ W2,      // [3, 128] row-major
    const float* __restrict__ b2,      // [3]
    float* __restrict__ out)           // [B, 3]
{
    const int b = blockIdx.x;
    const int t = threadIdx.x;          // 0..127
    const int wave = t >> 6;
    const int lane = t & 63;

    __shared__ float4 sf[896];          // 512 rows * 7 floats = 3584 f = 896 f4
    __shared__ float4 sc[384];          // 512 rows * 3 floats = 1536 f = 384 f4
    __shared__ float red[3][2];
    __shared__ float ge[3];

    const float4* fq = (const float4*)feats + (size_t)b * 896;
    const float4* cq = (const float4*)coors + (size_t)b * 384;

    // ---- coalesced staging: lane-contiguous float4 loads ----
    #pragma unroll
    for (int i = 0; i < 7; ++i) sf[i * 128 + t] = fq[i * 128 + t];
    #pragma unroll
    for (int i = 0; i < 3; ++i) sc[i * 128 + t] = cq[i * 128 + t];

    // hoist tiny per-thread weight loads above the barrier (latency overlap)
    const float w0 = W_tp[0], w1 = W_tp[1], w2 = W_tp[2], w3 = W_tp[3],
                w4 = W_tp[4], w5 = W_tp[5], w6 = W_tp[6];
    const float w1x = W1[t*3 + 0], w1y = W1[t*3 + 1], w1z = W1[t*3 + 2];
    const float bb1 = b1[t];
    const float w2a = W2[0*HID + t], w2b = W2[1*HID + t], w2c = W2[2*HID + t];

    __syncthreads();

    // ---- compute: thread t owns rows 4t..4t+3 (7 f4 feats, 3 f4 coors) ----
    const float4* sft = sf + t * 7;
    const float4* sct = sc + t * 3;
    float f[28];
    *(float4*)&f[0]  = sft[0];
    *(float4*)&f[4]  = sft[1];
    *(float4*)&f[8]  = sft[2];
    *(float4*)&f[12] = sft[3];
    *(float4*)&f[16] = sft[4];
    *(float4*)&f[20] = sft[5];
    *(float4*)&f[24] = sft[6];
    float c[12];
    *(float4*)&c[0] = sct[0];
    *(float4*)&c[4] = sct[1];
    *(float4*)&c[8] = sct[2];

    float s0 = f[0]*w0 + f[1]*w1 + f[2]*w2 + f[3]*w3 + f[4]*w4 + f[5]*w5 + f[6]*w6;
    float s1 = f[7]*w0 + f[8]*w1 + f[9]*w2 + f[10]*w3 + f[11]*w4 + f[12]*w5 + f[13]*w6;
    float s2 = f[14]*w0 + f[15]*w1 + f[16]*w2 + f[17]*w3 + f[18]*w4 + f[19]*w5 + f[20]*w6;
    float s3 = f[21]*w0 + f[22]*w1 + f[23]*w2 + f[24]*w3 + f[25]*w4 + f[26]*w5 + f[27]*w6;

    float ax = s0*c[0] + s1*c[3] + s2*c[6] + s3*c[9];
    float ay = s0*c[1] + s1*c[4] + s2*c[7] + s3*c[10];
    float az = s0*c[2] + s1*c[5] + s2*c[8] + s3*c[11];

    // ---- block reduction of (ax, ay, az) over 2 waves ----
    #pragma unroll
    for (int off = 32; off > 0; off >>= 1) {
        ax += __shfl_down(ax, off);
        ay += __shfl_down(ay, off);
        az += __shfl_down(az, off);
    }
    if (lane == 0) { red[0][wave] = ax; red[1][wave] = ay; red[2][wave] = az; }
    __syncthreads();
    if (t == 0) {
        const float alpha = 0.3779644730092272f;   // 1/sqrt(7)
        const float scale = alpha / 512.0f;        // mean over N=512 (exact)
        ge[0] = (red[0][0] + red[0][1]) * scale;
        ge[1] = (red[1][0] + red[1][1]) * scale;
        ge[2] = (red[2][0] + red[2][1]) * scale;
    }
    __syncthreads();

    // ---- MLP: h = relu(ge @ W1^T + b1); out = h @ W2^T + b2 ----
    float h = ge[0]*w1x + ge[1]*w1y + ge[2]*w1z + bb1;
    h = fmaxf(h, 0.f);
    float p0 = h * w2a;
    float p1 = h * w2b;
    float p2 = h * w2c;

    #pragma unroll
    for (int off = 32; off > 0; off >>= 1) {
        p0 += __shfl_down(p0, off);
        p1 += __shfl_down(p1, off);
        p2 += __shfl_down(p2, off);
    }
    if (lane == 0) { red[0][wave] = p0; red[1][wave] = p1; red[2][wave] = p2; }
    __syncthreads();
    if (t == 0) {
        out[b*3 + 0] = red[0][0] + red[0][1] + b2[0];
        out[b*3 + 1] = red[1][0] + red[1][1] + b2[1];
        out[b*3 + 2] = red[2][0] + red[2][1] + b2[2];
    }
}

extern "C" void kernel_launch(void* const* d_in, const int* in_sizes, int n_in,
                              void* d_out, int out_size, void* d_ws, size_t ws_size,
                              hipStream_t stream) {
    // setup_inputs order: feats, coors, adj_mat, W_tp, W1, b1, W2, b2
    const float* feats = (const float*)d_in[0];
    const float* coors = (const float*)d_in[1];
    // d_in[2] = adj_mat (unused by reference)
    const float* W_tp  = (const float*)d_in[3];
    const float* W1    = (const float*)d_in[4];
    const float* b1    = (const float*)d_in[5];
    const float* W2    = (const float*)d_in[6];
    const float* b2    = (const float*)d_in[7];
    float* out = (float*)d_out;

    const int B = 1024;
    dipole_e3nn_kernel<<<B, BLOCK, 0, stream>>>(feats, coors, W_tp, W1, b1, W2, b2, out);
}

// Round 4
// 10.842 us; speedup vs baseline: 1.0095x; 1.0095x over previous
//
#include <hip/hip_runtime.h>

// DipolePredictorE3NN: fused TP-scalar-gate + mean-pool + 3->128->3 MLP.
// R4: 256 threads/block, 2 rows/thread via float2 loads (14f = 7xf2, 6f = 3xf2).
// Doubles waves/SIMD vs R2 (4 vs 2) for latency hiding while keeping 10 load
// instructions per thread. No LDS on the load path (R3 regression lesson).
// adj_mat (d_in[2]) is unused by the reference.

#define BLOCK 256
#define HID 128

__global__ __launch_bounds__(BLOCK) void dipole_e3nn_kernel(
    const float* __restrict__ feats,   // [B, N, 7]
    const float* __restrict__ coors,   // [B, N, 3]
    const float* __restrict__ W_tp,    // [7]
    const float* __restrict__ W1,      // [128, 3] row-major
    const float* __restrict__ b1,      // [128]
    const float* __restrict__ W2,      // [3, 128] row-major
    const float* __restrict__ b2,      // [3]
    float* __restrict__ out)           // [B, 3]
{
    const int b = blockIdx.x;
    const int t = threadIdx.x;          // 0..255, owns rows 2t, 2t+1
    const int wave = t >> 6;            // 0..3
    const int lane = t & 63;

    // feats batch = 3584 floats = 1792 float2; 7 f2 per thread.
    const float2* fq = (const float2*)feats + (size_t)b * 1792 + t * 7;
    // coors batch = 1536 floats = 768 float2; 3 f2 per thread.
    const float2* cq = (const float2*)coors + (size_t)b * 768 + t * 3;

    const float2 f0 = fq[0], f1 = fq[1], f2v = fq[2], f3 = fq[3],
                 f4v = fq[4], f5 = fq[5], f6 = fq[6];
    const float2 c0 = cq[0], c1 = cq[1], c2 = cq[2];

    const float w0 = W_tp[0], w1 = W_tp[1], w2 = W_tp[2], w3 = W_tp[3],
                w4 = W_tp[4], w5 = W_tp[5], w6 = W_tp[6];

    // MLP weights for lanes that own a hidden unit (waves 0-1 only)
    float w1x = 0.f, w1y = 0.f, w1z = 0.f, bb1 = 0.f;
    float w2a = 0.f, w2b = 0.f, w2c = 0.f;
    if (t < HID) {
        w1x = W1[t*3 + 0]; w1y = W1[t*3 + 1]; w1z = W1[t*3 + 2];
        bb1 = b1[t];
        w2a = W2[0*HID + t]; w2b = W2[1*HID + t]; w2c = W2[2*HID + t];
    }

    // row 2t:   feats = f0.x f0.y f1.x f1.y f2v.x f2v.y f3.x ; coors = c0.x c0.y c1.x
    // row 2t+1: feats = f3.y f4v.x f4v.y f5.x f5.y f6.x f6.y ; coors = c1.y c2.x c2.y
    const float s0 = f0.x*w0 + f0.y*w1 + f1.x*w2 + f1.y*w3 + f2v.x*w4 + f2v.y*w5 + f3.x*w6;
    const float s1 = f3.y*w0 + f4v.x*w1 + f4v.y*w2 + f5.x*w3 + f5.y*w4 + f6.x*w5 + f6.y*w6;

    float ax = s0*c0.x + s1*c1.y;
    float ay = s0*c0.y + s1*c2.x;
    float az = s0*c1.x + s1*c2.y;

    // ---- block reduction of (ax, ay, az) over 4 waves ----
    __shared__ float red[3][4];
    __shared__ float ge[3];
    #pragma unroll
    for (int off = 32; off > 0; off >>= 1) {
        ax += __shfl_down(ax, off);
        ay += __shfl_down(ay, off);
        az += __shfl_down(az, off);
    }
    if (lane == 0) { red[0][wave] = ax; red[1][wave] = ay; red[2][wave] = az; }
    __syncthreads();
    if (t == 0) {
        const float alpha = 0.3779644730092272f;   // 1/sqrt(7)
        const float scale = alpha / 512.0f;        // mean over N=512 (exact)
        ge[0] = (red[0][0] + red[0][1] + red[0][2] + red[0][3]) * scale;
        ge[1] = (red[1][0] + red[1][1] + red[1][2] + red[1][3]) * scale;
        ge[2] = (red[2][0] + red[2][1] + red[2][2] + red[2][3]) * scale;
    }
    __syncthreads();

    // ---- MLP: h = relu(ge @ W1^T + b1); out = h @ W2^T + b2 ----
    float p0 = 0.f, p1 = 0.f, p2 = 0.f;
    if (t < HID) {
        float h = ge[0]*w1x + ge[1]*w1y + ge[2]*w1z + bb1;
        h = fmaxf(h, 0.f);
        p0 = h * w2a;
        p1 = h * w2b;
        p2 = h * w2c;
    }
    #pragma unroll
    for (int off = 32; off > 0; off >>= 1) {
        p0 += __shfl_down(p0, off);
        p1 += __shfl_down(p1, off);
        p2 += __shfl_down(p2, off);
    }
    if (lane == 0) { red[0][wave] = p0; red[1][wave] = p1; red[2][wave] = p2; }
    __syncthreads();
    if (t == 0) {
        out[b*3 + 0] = red[0][0] + red[0][1] + b2[0];
        out[b*3 + 1] = red[1][0] + red[1][1] + b2[1];
        out[b*3 + 2] = red[2][0] + red[2][1] + b2[2];
    }
}

extern "C" void kernel_launch(void* const* d_in, const int* in_sizes, int n_in,
                              void* d_out, int out_size, void* d_ws, size_t ws_size,
                              hipStream_t stream) {
    // setup_inputs order: feats, coors, adj_mat, W_tp, W1, b1, W2, b2
    const float* feats = (const float*)d_in[0];
    const float* coors = (const float*)d_in[1];
    // d_in[2] = adj_mat (unused by reference)
    const float* W_tp  = (const float*)d_in[3];
    const float* W1    = (const float*)d_in[4];
    const float* b1    = (const float*)d_in[5];
    const float* W2    = (const float*)d_in[6];
    const float* b2    = (const float*)d_in[7];
    float* out = (float*)d_out;

    const int B = 1024;
    dipole_e3nn_kernel<<<B, BLOCK, 0, stream>>>(feats, coors, W_tp, W1, b1, W2, b2, out);
}

// Round 5
// 9.727 us; speedup vs baseline: 1.1252x; 1.1146x over previous
//
#include <hip/hip_runtime.h>

// DipolePredictorE3NN: fused TP-scalar-gate + mean-pool + 3->128->3 MLP.
// R5: R2's float4 pattern (4 rows/thread, 7+3 f4 loads) kept verbatim, but
// 256-thread blocks each process TWO batch elements as two independent
// 128-thread groups -> grid 512 (halved dispatch count).
// adj_mat (d_in[2]) is unused by the reference.

#define BLOCK 256
#define HID 128

__global__ __launch_bounds__(BLOCK) void dipole_e3nn_kernel(
    const float* __restrict__ feats,   // [B, N, 7]
    const float* __restrict__ coors,   // [B, N, 3]
    const float* __restrict__ W_tp,    // [7]
    const float* __restrict__ W1,      // [128, 3] row-major
    const float* __restrict__ b1,      // [128]
    const float* __restrict__ W2,      // [3, 128] row-major
    const float* __restrict__ b2,      // [3]
    float* __restrict__ out)           // [B, 3]
{
    const int t  = threadIdx.x;         // 0..255
    const int g  = t >> 7;              // group 0/1 -> batch element
    const int tt = t & 127;             // 0..127 within group
    const int b  = blockIdx.x * 2 + g;
    const int wave = t >> 6;            // 0..3 (block-wide)
    const int lane = t & 63;
    const int gwave = tt >> 6;          // 0..1 within group

    const float w0 = W_tp[0], w1 = W_tp[1], w2 = W_tp[2], w3 = W_tp[3],
                w4 = W_tp[4], w5 = W_tp[5], w6 = W_tp[6];

    // feats batch = 896 float4; 7 per thread. coors batch = 384 float4; 3 per thread.
    const float4* fq = (const float4*)feats + (size_t)b * 896 + tt * 7;
    const float4* cq = (const float4*)coors + (size_t)b * 384 + tt * 3;

    float f[28];
    *(float4*)&f[0]  = fq[0];
    *(float4*)&f[4]  = fq[1];
    *(float4*)&f[8]  = fq[2];
    *(float4*)&f[12] = fq[3];
    *(float4*)&f[16] = fq[4];
    *(float4*)&f[20] = fq[5];
    *(float4*)&f[24] = fq[6];
    float c[12];
    *(float4*)&c[0] = cq[0];
    *(float4*)&c[4] = cq[1];
    *(float4*)&c[8] = cq[2];

    // per-thread MLP weights (hidden unit tt)
    const float w1x = W1[tt*3 + 0], w1y = W1[tt*3 + 1], w1z = W1[tt*3 + 2];
    const float bb1 = b1[tt];
    const float w2a = W2[0*HID + tt], w2b = W2[1*HID + tt], w2c = W2[2*HID + tt];

    float s0 = f[0]*w0 + f[1]*w1 + f[2]*w2 + f[3]*w3 + f[4]*w4 + f[5]*w5 + f[6]*w6;
    float s1 = f[7]*w0 + f[8]*w1 + f[9]*w2 + f[10]*w3 + f[11]*w4 + f[12]*w5 + f[13]*w6;
    float s2 = f[14]*w0 + f[15]*w1 + f[16]*w2 + f[17]*w3 + f[18]*w4 + f[19]*w5 + f[20]*w6;
    float s3 = f[21]*w0 + f[22]*w1 + f[23]*w2 + f[24]*w3 + f[25]*w4 + f[26]*w5 + f[27]*w6;

    float ax = s0*c[0] + s1*c[3] + s2*c[6] + s3*c[9];
    float ay = s0*c[1] + s1*c[4] + s2*c[7] + s3*c[10];
    float az = s0*c[2] + s1*c[5] + s2*c[8] + s3*c[11];

    // ---- per-group reduction: 2 waves per group, waves are group-pure ----
    __shared__ float red[3][4];         // indexed by block-wide wave id
    __shared__ float ge[2][3];
    #pragma unroll
    for (int off = 32; off > 0; off >>= 1) {
        ax += __shfl_down(ax, off);
        ay += __shfl_down(ay, off);
        az += __shfl_down(az, off);
    }
    if (lane == 0) { red[0][wave] = ax; red[1][wave] = ay; red[2][wave] = az; }
    __syncthreads();
    if (tt == 0) {  // one leader per group (t==0 and t==128)
        const float alpha = 0.3779644730092272f;   // 1/sqrt(7)
        const float scale = alpha / 512.0f;        // mean over N=512 (exact)
        ge[g][0] = (red[0][g*2] + red[0][g*2+1]) * scale;
        ge[g][1] = (red[1][g*2] + red[1][g*2+1]) * scale;
        ge[g][2] = (red[2][g*2] + red[2][g*2+1]) * scale;
    }
    __syncthreads();

    // ---- MLP: h = relu(ge @ W1^T + b1); out = h @ W2^T + b2 ----
    float h = ge[g][0]*w1x + ge[g][1]*w1y + ge[g][2]*w1z + bb1;
    h = fmaxf(h, 0.f);
    float p0 = h * w2a;
    float p1 = h * w2b;
    float p2 = h * w2c;

    #pragma unroll
    for (int off = 32; off > 0; off >>= 1) {
        p0 += __shfl_down(p0, off);
        p1 += __shfl_down(p1, off);
        p2 += __shfl_down(p2, off);
    }
    if (lane == 0) { red[0][wave] = p0; red[1][wave] = p1; red[2][wave] = p2; }
    __syncthreads();
    if (tt == 0) {
        out[b*3 + 0] = red[0][g*2] + red[0][g*2+1] + b2[0];
        out[b*3 + 1] = red[1][g*2] + red[1][g*2+1] + b2[1];
        out[b*3 + 2] = red[2][g*2] + red[2][g*2+1] + b2[2];
    }
}

extern "C" void kernel_launch(void* const* d_in, const int* in_sizes, int n_in,
                              void* d_out, int out_size, void* d_ws, size_t ws_size,
                              hipStream_t stream) {
    // setup_inputs order: feats, coors, adj_mat, W_tp, W1, b1, W2, b2
    const float* feats = (const float*)d_in[0];
    const float* coors = (const float*)d_in[1];
    // d_in[2] = adj_mat (unused by reference)
    const float* W_tp  = (const float*)d_in[3];
    const float* W1    = (const float*)d_in[4];
    const float* b1    = (const float*)d_in[5];
    const float* W2    = (const float*)d_in[6];
    const float* b2    = (const float*)d_in[7];
    float* out = (float*)d_out;

    dipole_e3nn_kernel<<<512, BLOCK, 0, stream>>>(feats, coors, W_tp, W1, b1, W2, b2, out);
}